// Round 10
// baseline (167.452 us; speedup 1.0000x reference)
//
#include <hip/hip_runtime.h>

#define NBLK 256
#define FPAD 16   // 64 B per flag slot

typedef float v2f __attribute__((ext_vector_type(2)));

#define AG_LD(p)    __hip_atomic_load((p), __ATOMIC_RELAXED, __HIP_MEMORY_SCOPE_AGENT)
#define AG_ST(p, v) __hip_atomic_store((p), (v), __ATOMIC_RELAXED, __HIP_MEMORY_SCOPE_AGENT)

// Fan-out grid barrier (validated R5-R9). fence only after the transpose
// phase; later cross-block data moves via agent-scope relaxed atomics so
// each XCD's L2 stays warm with weights.
__device__ __forceinline__ void gridbar(int n, unsigned* flags, unsigned* rel,
                                        int bid, bool fence) {
    __syncthreads();
    if (threadIdx.x == 0)
        __hip_atomic_store(&flags[bid * FPAD], (unsigned)n, __ATOMIC_RELEASE,
                           __HIP_MEMORY_SCOPE_AGENT);
    if (bid == 0) {
        if (threadIdx.x < NBLK) {
            while ((int)__hip_atomic_load(&flags[threadIdx.x * FPAD],
                                          __ATOMIC_RELAXED,
                                          __HIP_MEMORY_SCOPE_AGENT) < n)
                __builtin_amdgcn_s_sleep(1);
        }
        __syncthreads();
        if (threadIdx.x < 16)
            __hip_atomic_store(&rel[(n * 16 + threadIdx.x) * FPAD], (unsigned)n,
                               __ATOMIC_RELEASE, __HIP_MEMORY_SCOPE_AGENT);
    } else {
        if (threadIdx.x == 0) {
            while ((int)__hip_atomic_load(&rel[(n * 16 + (bid & 15)) * FPAD],
                                          __ATOMIC_RELAXED,
                                          __HIP_MEMORY_SCOPE_AGENT) < n)
                __builtin_amdgcn_s_sleep(1);
        }
    }
    if (fence) __builtin_amdgcn_fence(__ATOMIC_ACQUIRE, "agent");
    __syncthreads();
}

// Per-batch softmax combine + sigmoid + U2 matvec + updB (validated R9).
// 512 threads: c=tid&255, rq=tid>>8.
__device__ __forceinline__ float phaseB(int i, int b, int c, int rq,
                                        const float* __restrict__ part,
                                        const float* __restrict__ WtB,
                                        const float* __restrict__ updB,
                                        float* sc, float* aggl) {
    float M = -1e30f, den = 0.f, num = 0.f;
    const int par = i & 1;
    #pragma unroll
    for (int j = rq * 8; j < rq * 8 + 8; ++j) {
        const float* pp = part + (size_t)(par * 256 + b * 16 + j) * 768;
        const float mj = AG_LD(pp + c);
        const float dj = AG_LD(pp + 256 + c);
        const float nj = AG_LD(pp + 512 + c);
        const float Mn = fmaxf(M, mj);
        const float s = __expf(M - Mn), e = __expf(mj - Mn);
        den = den * s + dj * e;
        num = num * s + nj * e;
        M = Mn;
    }
    sc[rq * 256 + c] = M;
    sc[512 + rq * 256 + c] = den;
    sc[1024 + rq * 256 + c] = num;
    __syncthreads();
    if (rq == 0) {
        const float m0 = sc[c], m1 = sc[256 + c];
        const float Mx = fmaxf(m0, m1);
        const float s0 = __expf(m0 - Mx), s1 = __expf(m1 - Mx);
        const float dd = sc[512 + c] * s0 + sc[768 + c] * s1;
        const float nn = sc[1024 + c] * s0 + sc[1280 + c] * s1;
        aggl[c] = 1.f / (1.f + __expf(-(nn / dd)));
    }
    __syncthreads();
    const float4* U2q = (const float4*)(WtB + (size_t)(9 + i) * 65536);
    const int kg0 = rq * 32;
    float4 buf[8];
    #pragma unroll
    for (int j = 0; j < 8; ++j) buf[j] = U2q[(size_t)(kg0 + j) * 256 + c];
    v2f au = {0.f, 0.f};
    #pragma unroll
    for (int ph = 0; ph < 4; ++ph) {
        #pragma unroll
        for (int j = 0; j < 8; ++j) {
            const float4 w4 = buf[j];
            if (ph < 3) buf[j] = U2q[(size_t)(kg0 + (ph + 1) * 8 + j) * 256 + c];
            const float4 ag = *(const float4*)&aggl[(kg0 + ph * 8 + j) * 4];
            au += (v2f){ag.x, ag.y} * (v2f){w4.x, w4.y};
            au += (v2f){ag.z, ag.w} * (v2f){w4.z, w4.w};
        }
    }
    __syncthreads();
    sc[rq * 256 + c] = au.x + au.y;
    __syncthreads();
    return sc[c] + sc[256 + c] + updB[i * 256 + c];
}

// Persistent kernel. Block = 8 rows. GEMM phases k-sliced across 8 waves
// (wave w owns k in [32w, 32w+32)); cross-wave reduce via 32KB LDS partials
// in two row-halves. Thread (c, rq) owns output rows {2rq,2rq+1,2rq+4,2rq+5}.
__global__ __launch_bounds__(512, 2) void fused_k(
    const float* __restrict__ feat,   // [16][128][256]
    const float* __restrict__ mask,   // [16][128]
    const float* __restrict__ aggW,   // [3][256][256]
    const float* __restrict__ aggB,   // [3][256]
    const float* __restrict__ attnW,  // [3][256][512]
    const float* __restrict__ updW,   // [3][256][512]
    const float* __restrict__ updB,   // [3][256]
    float* __restrict__ WtB,          // 12 * 65536 packed k-quad layout
    float* __restrict__ part,         // 2 * 256 * 768 (cross-block partials)
    unsigned* flags, unsigned* rel,
    float* __restrict__ out)
{
    __shared__ float ldsa[14080];     // 56.3 KB
    float*  hidl = ldsa;              // [8][256]
    float*  xl   = ldsa + 2048;       // [8][256]
    float2* red2 = (float2*)(ldsa + 4096);  // [16][256] float2 = 32 KB
    float*  sc   = ldsa + 12288;      // [1536]
    float*  aggl = ldsa + 13824;      // [256]

    const int bid  = blockIdx.x;
    const int tid  = threadIdx.x;
    const int lane = tid & 63;
    const int w    = tid >> 6;        // wave id 0..7 (k-slice owner)
    const int c    = tid & 255;
    const int rq   = tid >> 8;        // 0..1
    const int b    = bid >> 4, jj = bid & 15;
    const int row0 = b * 128 + jj * 8;

    // ---- P0: transpose+pack 12 weight mats (blocks 0..191) — validated R8/R9
    if (bid < 192) {
        float (*Tl)[65] = (float (*)[65])ldsa;
        const int m = bid >> 4, t = bid & 15, tr = t >> 2, tc = t & 3;
        const float* src; int stride, off;
        if (m < 3)      { src = aggW  + (size_t)m * 65536;        stride = 256; off = 0;   }
        else if (m < 6) { src = attnW + (size_t)(m - 3) * 131072; stride = 512; off = 0;   }
        else if (m < 9) { src = updW  + (size_t)(m - 6) * 131072; stride = 512; off = 0;   }
        else            { src = updW  + (size_t)(m - 9) * 131072; stride = 512; off = 256; }
        float* dst = WtB + (size_t)m * 65536;
        #pragma unroll
        for (int it = 0; it < 2; ++it) {
            const int j = it * 512 + tid, row = j >> 4, q = (j & 15) * 4;
            const float4 v = *(const float4*)(src + (size_t)(tr * 64 + row) * stride + off + tc * 64 + q);
            Tl[row][q + 0] = v.x; Tl[row][q + 1] = v.y;
            Tl[row][q + 2] = v.z; Tl[row][q + 3] = v.w;
        }
        __syncthreads();
        #pragma unroll
        for (int it = 0; it < 2; ++it) {
            const int j = it * 512 + tid, kgl = j >> 6, cl = j & 63;
            float4 v;
            v.x = Tl[cl][kgl * 4 + 0]; v.y = Tl[cl][kgl * 4 + 1];
            v.z = Tl[cl][kgl * 4 + 2]; v.w = Tl[cl][kgl * 4 + 3];
            *(float4*)(dst + (size_t)(tc * 16 + kgl) * 1024 + (tr * 64 + cl) * 4) = v;
        }
    }
    gridbar(1, flags, rel, bid, true);   // fence: publish WtB, kill poison

    v2f xu01 = {0.f, 0.f}, xu23 = {0.f, 0.f};
    float accU = 0.f;

    for (int i = 0; i < 3; ++i) {
        if (i > 0)
            accU = phaseB(i - 1, b, c, rq, part, WtB, updB, sc, aggl);

        // ---- build hid rows in LDS [r][k]
        if (i == 0) {
            #pragma unroll
            for (int r = 0; r < 4; ++r) {
                const int rl = rq * 4 + r;
                hidl[rl * 256 + c] = feat[(size_t)(row0 + rl) * 256 + c] * mask[row0 + rl];
            }
        } else {
            hidl[(2 * rq)     * 256 + c] = (xu01.x + accU) * mask[row0 + 2 * rq];
            hidl[(2 * rq + 1) * 256 + c] = (xu01.y + accU) * mask[row0 + 2 * rq + 1];
            hidl[(2 * rq + 4) * 256 + c] = (xu23.x + accU) * mask[row0 + 2 * rq + 4];
            hidl[(2 * rq + 5) * 256 + c] = (xu23.y + accU) * mask[row0 + 2 * rq + 5];
        }
        __syncthreads();

        // ---- P1: x = hid @ aggW^T + aggB (k-sliced over waves)
        v2f s01, s23;
        {
            const float4* Wq = (const float4*)(WtB + (size_t)i * 65536);
            const int kg0 = w * 8;
            v2f acc[4][4];
            #pragma unroll
            for (int rp = 0; rp < 4; ++rp)
                #pragma unroll
                for (int cc = 0; cc < 4; ++cc) acc[rp][cc] = (v2f){0.f, 0.f};
            float4 wc[4];
            #pragma unroll
            for (int cc = 0; cc < 4; ++cc) wc[cc] = Wq[(size_t)kg0 * 256 + lane + 64 * cc];
            #pragma unroll
            for (int g = 0; g < 8; ++g) {
                float4 wn[4];
                const int gn = (g < 7) ? g + 1 : 7;
                #pragma unroll
                for (int cc = 0; cc < 4; ++cc)
                    wn[cc] = Wq[(size_t)(kg0 + gn) * 256 + lane + 64 * cc];
                const int kq = (kg0 + g) * 4;
                #pragma unroll
                for (int rp = 0; rp < 4; ++rp) {
                    const float4 a0 = *(const float4*)&hidl[(2 * rp) * 256 + kq];
                    const float4 a1 = *(const float4*)&hidl[(2 * rp + 1) * 256 + kq];
                    #pragma unroll
                    for (int cc = 0; cc < 4; ++cc) {
                        acc[rp][cc] += (v2f){a0.x, a1.x} * wc[cc].x;
                        acc[rp][cc] += (v2f){a0.y, a1.y} * wc[cc].y;
                        acc[rp][cc] += (v2f){a0.z, a1.z} * wc[cc].z;
                        acc[rp][cc] += (v2f){a0.w, a1.w} * wc[cc].w;
                    }
                }
                #pragma unroll
                for (int cc = 0; cc < 4; ++cc) wc[cc] = wn[cc];
            }
            #pragma unroll
            for (int half = 0; half < 2; ++half) {
                #pragma unroll
                for (int rp = 0; rp < 2; ++rp)
                    #pragma unroll
                    for (int cc = 0; cc < 4; ++cc)
                        red2[(w * 2 + rp) * 256 + lane + 64 * cc] =
                            make_float2(acc[half * 2 + rp][cc].x, acc[half * 2 + rp][cc].y);
                __syncthreads();
                v2f s = {0.f, 0.f};
                #pragma unroll
                for (int wi = 0; wi < 8; ++wi) {
                    const float2 v = red2[(wi * 2 + rq) * 256 + c];
                    s += (v2f){v.x, v.y};
                }
                if (half == 0) s01 = s; else s23 = s;
                __syncthreads();
            }
            const float bb = aggB[i * 256 + c];
            xl[(2 * rq)     * 256 + c] = s01.x + bb;
            xl[(2 * rq + 1) * 256 + c] = s01.y + bb;
            xl[(2 * rq + 4) * 256 + c] = s23.x + bb;
            xl[(2 * rq + 5) * 256 + c] = s23.y + bb;
        }
        __syncthreads();

        // ---- P2: p = x@W1^T and xU1 = x@U1^T (shared A-reads, k-sliced)
        v2f p01, p23;
        {
            const float4* W1q = (const float4*)(WtB + (size_t)(3 + i) * 65536);
            const float4* U1q = (const float4*)(WtB + (size_t)(6 + i) * 65536);
            const int kg0 = w * 8;
            v2f pa[4][4], ua[4][4];
            #pragma unroll
            for (int rp = 0; rp < 4; ++rp)
                #pragma unroll
                for (int cc = 0; cc < 4; ++cc) {
                    pa[rp][cc] = (v2f){0.f, 0.f};
                    ua[rp][cc] = (v2f){0.f, 0.f};
                }
            float4 w1c[4], u1c[4];
            #pragma unroll
            for (int cc = 0; cc < 4; ++cc) {
                w1c[cc] = W1q[(size_t)kg0 * 256 + lane + 64 * cc];
                u1c[cc] = U1q[(size_t)kg0 * 256 + lane + 64 * cc];
            }
            #pragma unroll
            for (int g = 0; g < 8; ++g) {
                float4 w1n[4], u1n[4];
                const int gn = (g < 7) ? g + 1 : 7;
                #pragma unroll
                for (int cc = 0; cc < 4; ++cc) {
                    w1n[cc] = W1q[(size_t)(kg0 + gn) * 256 + lane + 64 * cc];
                    u1n[cc] = U1q[(size_t)(kg0 + gn) * 256 + lane + 64 * cc];
                }
                const int kq = (kg0 + g) * 4;
                #pragma unroll
                for (int rp = 0; rp < 4; ++rp) {
                    const float4 a0 = *(const float4*)&xl[(2 * rp) * 256 + kq];
                    const float4 a1 = *(const float4*)&xl[(2 * rp + 1) * 256 + kq];
                    #pragma unroll
                    for (int cc = 0; cc < 4; ++cc) {
                        pa[rp][cc] += (v2f){a0.x, a1.x} * w1c[cc].x;
                        pa[rp][cc] += (v2f){a0.y, a1.y} * w1c[cc].y;
                        pa[rp][cc] += (v2f){a0.z, a1.z} * w1c[cc].z;
                        pa[rp][cc] += (v2f){a0.w, a1.w} * w1c[cc].w;
                        ua[rp][cc] += (v2f){a0.x, a1.x} * u1c[cc].x;
                        ua[rp][cc] += (v2f){a0.y, a1.y} * u1c[cc].y;
                        ua[rp][cc] += (v2f){a0.z, a1.z} * u1c[cc].z;
                        ua[rp][cc] += (v2f){a0.w, a1.w} * u1c[cc].w;
                    }
                }
                #pragma unroll
                for (int cc = 0; cc < 4; ++cc) { w1c[cc] = w1n[cc]; u1c[cc] = u1n[cc]; }
            }
            // reduce p then u, each in two row-halves
            #pragma unroll
            for (int half = 0; half < 2; ++half) {
                #pragma unroll
                for (int rp = 0; rp < 2; ++rp)
                    #pragma unroll
                    for (int cc = 0; cc < 4; ++cc)
                        red2[(w * 2 + rp) * 256 + lane + 64 * cc] =
                            make_float2(pa[half * 2 + rp][cc].x, pa[half * 2 + rp][cc].y);
                __syncthreads();
                v2f s = {0.f, 0.f};
                #pragma unroll
                for (int wi = 0; wi < 8; ++wi) {
                    const float2 v = red2[(wi * 2 + rq) * 256 + c];
                    s += (v2f){v.x, v.y};
                }
                if (half == 0) p01 = s; else p23 = s;
                __syncthreads();
            }
            #pragma unroll
            for (int half = 0; half < 2; ++half) {
                #pragma unroll
                for (int rp = 0; rp < 2; ++rp)
                    #pragma unroll
                    for (int cc = 0; cc < 4; ++cc)
                        red2[(w * 2 + rp) * 256 + lane + 64 * cc] =
                            make_float2(ua[half * 2 + rp][cc].x, ua[half * 2 + rp][cc].y);
                __syncthreads();
                v2f s = {0.f, 0.f};
                #pragma unroll
                for (int wi = 0; wi < 8; ++wi) {
                    const float2 v = red2[(wi * 2 + rq) * 256 + c];
                    s += (v2f){v.x, v.y};
                }
                if (half == 0) xu01 = s; else xu23 = s;
                __syncthreads();
            }
        }

        // ---- online-softmax partial over this thread's 4 rows
        {
            const float xv0 = xl[(2 * rq)     * 256 + c];
            const float xv1 = xl[(2 * rq + 1) * 256 + c];
            const float xv2 = xl[(2 * rq + 4) * 256 + c];
            const float xv3 = xl[(2 * rq + 5) * 256 + c];
            const float m4 = fmaxf(fmaxf(p01.x, p01.y), fmaxf(p23.x, p23.y));
            const float e0 = __expf(p01.x - m4), e1 = __expf(p01.y - m4);
            const float e2 = __expf(p23.x - m4), e3 = __expf(p23.y - m4);
            sc[rq * 256 + c]        = m4;
            sc[512 + rq * 256 + c]  = e0 + e1 + e2 + e3;
            sc[1024 + rq * 256 + c] = e0 * xv0 + e1 * xv1 + e2 * xv2 + e3 * xv3;
        }
        __syncthreads();
        if (rq == 0) {
            const float m0 = sc[c], m1 = sc[256 + c];
            const float Mx = fmaxf(m0, m1);
            const float s0 = __expf(m0 - Mx), s1 = __expf(m1 - Mx);
            const float dd = sc[512 + c] * s0 + sc[768 + c] * s1;
            const float nn = sc[1024 + c] * s0 + sc[1280 + c] * s1;
            float* pb = part + (size_t)((i & 1) * 256 + bid) * 768;
            AG_ST(pb + c, Mx);
            AG_ST(pb + 256 + c, dd);
            AG_ST(pb + 512 + c, nn);
        }
        gridbar(i + 2, flags, rel, bid, false);   // no fence: L2 stays warm
    }

    // ---- final combine + epilogue: out = xU1 + accU
    accU = phaseB(2, b, c, rq, part, WtB, updB, sc, aggl);
    out[(size_t)(row0 + 2 * rq)     * 256 + c] = xu01.x + accU;
    out[(size_t)(row0 + 2 * rq + 1) * 256 + c] = xu01.y + accU;
    out[(size_t)(row0 + 2 * rq + 4) * 256 + c] = xu23.x + accU;
    out[(size_t)(row0 + 2 * rq + 5) * 256 + c] = xu23.y + accU;
}

extern "C" void kernel_launch(void* const* d_in, const int* in_sizes, int n_in,
                              void* d_out, int out_size, void* d_ws, size_t ws_size,
                              hipStream_t stream) {
    const float* feat  = (const float*)d_in[0];
    const float* mask  = (const float*)d_in[1];
    const float* aggW  = (const float*)d_in[2];
    const float* aggB  = (const float*)d_in[3];
    const float* attnW = (const float*)d_in[4];
    // d_in[5] = attnB: cancels in softmax (constant along the s axis)
    const float* updW  = (const float*)d_in[6];
    const float* updB  = (const float*)d_in[7];

    float* WtB  = (float*)d_ws;                        // 12 * 65536 floats
    float* part = WtB + 12 * 65536;                    // 2 * 256 * 768 floats
    unsigned* flags = (unsigned*)(part + 2 * 256 * 768);
    unsigned* rel   = flags + NBLK * FPAD;

    fused_k<<<NBLK, 512, 0, stream>>>(
        feat, mask, aggW, aggB, attnW, updW, updB,
        WtB, part, flags, rel, (float*)d_out);
}